// Round 1
// baseline (462.774 us; speedup 1.0000x reference)
//
#include <hip/hip_runtime.h>
#include <hip/hip_bf16.h>
#include <stdint.h>

namespace {

constexpr int kB = 2;
constexpr int kS = 2048;
constexpr int kD = 2048;
constexpr int kH = 16;
constexpr int kKV = 4;
constexpr int kHd = 128;
constexpr int kM = kB * kS;               // 4096 token rows
constexpr int kQKVN = kD + 2 * kKV * kHd; // 3072 (q 0..2047, k 2048..2559, v 2560..3071)

using bf = __bf16;
typedef bf bf16x8 __attribute__((ext_vector_type(8)));
typedef float f32x4 __attribute__((ext_vector_type(4)));

__device__ __forceinline__ f32x4 mfma16(bf16x8 a, bf16x8 b, f32x4 c) {
  return __builtin_amdgcn_mfma_f32_16x16x32_bf16(a, b, c, 0, 0, 0);
}

__device__ __forceinline__ void gload_lds16(const bf* g, bf* l) {
  __builtin_amdgcn_global_load_lds(
      (const __attribute__((address_space(1))) void*)(uintptr_t)g,
      (__attribute__((address_space(3))) void*)l, 16, 0, 0);
}

// ---------------- fp32 -> bf16 convert ----------------
__global__ __launch_bounds__(256) void cvt_kernel(const float* __restrict__ src,
                                                  bf* __restrict__ dst, int n4) {
  int i = blockIdx.x * 256 + threadIdx.x;
  if (i >= n4) return;
  float4 v = reinterpret_cast<const float4*>(src)[i];
  union { bf h[4]; uint2 u; } o;
  o.h[0] = (bf)v.x; o.h[1] = (bf)v.y; o.h[2] = (bf)v.z; o.h[3] = (bf)v.w;
  reinterpret_cast<uint2*>(dst)[i] = o.u;
}

// ---------------- C = A * B^T  (A[M][K], B[N][K], both K-contig bf16) ----------------
// m97 structure: 128x128 tile, BK=64, global_load_lds w/ pre-swizzled source,
// XOR-swizzled ds_read_b128 frags (T2), 4 waves of 64x64.
template <typename CT>
__global__ __launch_bounds__(256) void gemm_bt(const bf* __restrict__ A, int lda,
                                               const bf* __restrict__ Bm, int ldb,
                                               CT* __restrict__ C, int ldc, int K) {
  __shared__ bf As[128 * 64];
  __shared__ bf Bs[128 * 64];
  const int tid = threadIdx.x;
  const int w = tid >> 6, lane = tid & 63;
  const int r16 = lane & 15, kg = lane >> 4;
  const int bm = blockIdx.y * 128, bn = blockIdx.x * 128;
  const int wy = (w >> 1) * 64, wx = (w & 1) * 64;
  f32x4 acc[4][4] = {};
  for (int kt = 0; kt < K; kt += 64) {
    __syncthreads();
#pragma unroll
    for (int r = 0; r < 4; r++) {
      int u = r * 256 + tid;                       // 16B unit, 8 per 128B row
      int row = u >> 3;
      int cb = ((u & 7) * 16) ^ ((row & 7) << 4);  // pre-swizzle the SOURCE
      gload_lds16(A + (size_t)(bm + row) * lda + kt + (cb >> 1),
                  As + (size_t)(r * 256 + w * 64) * 8);
      gload_lds16(Bm + (size_t)(bn + row) * ldb + kt + (cb >> 1),
                  Bs + (size_t)(r * 256 + w * 64) * 8);
    }
    __syncthreads();
#pragma unroll
    for (int ks = 0; ks < 2; ks++) {
      bf16x8 af[4], bfr[4];
#pragma unroll
      for (int m = 0; m < 4; m++) {
        int row = wy + m * 16 + r16;
        af[m] = *reinterpret_cast<const bf16x8*>(
            reinterpret_cast<const char*>(As) + row * 128 +
            ((ks * 64 + kg * 16) ^ ((row & 7) << 4)));
      }
#pragma unroll
      for (int n = 0; n < 4; n++) {
        int row = wx + n * 16 + r16;
        bfr[n] = *reinterpret_cast<const bf16x8*>(
            reinterpret_cast<const char*>(Bs) + row * 128 +
            ((ks * 64 + kg * 16) ^ ((row & 7) << 4)));
      }
#pragma unroll
      for (int m = 0; m < 4; m++)
#pragma unroll
        for (int n = 0; n < 4; n++)
          acc[m][n] = mfma16(af[m], bfr[n], acc[m][n]);
    }
  }
  // C/D layout (m89 verified): col = lane&15, row = (lane>>4)*4 + reg
#pragma unroll
  for (int m = 0; m < 4; m++)
#pragma unroll
    for (int n = 0; n < 4; n++)
#pragma unroll
      for (int r = 0; r < 4; r++) {
        int row = bm + wy + m * 16 + kg * 4 + r;
        int col = bn + wx + n * 16 + r16;
        C[(size_t)row * ldc + col] = (CT)acc[m][n][r];
      }
}

// ---------------- RMSNorm + RoPE + q_gain, in place on qkv (q & k cols) ----------------
// One wave per 128-elem head vector; lane owns the rope pair (d, d+64).
__global__ __launch_bounds__(256) void normrope(bf* __restrict__ qkv,
                                                const float* __restrict__ qgain) {
  const int tid = threadIdx.x;
  const int w = tid >> 6, lane = tid & 63;
  int v = blockIdx.x * 4 + w;             // 0 .. B*S*(H+KV)-1 = 81919
  int b = v / (kS * (kH + kKV));
  int rem = v % (kS * (kH + kKV));
  int s = rem / (kH + kKV);
  int j = rem % (kH + kKV);               // 0..15 q heads, 16..19 kv heads
  int colbase = (j < kH) ? j * kHd : kD + (j - kH) * kHd;
  size_t base = (size_t)(b * kS + s) * kQKVN + colbase;
  float e1 = (float)qkv[base + lane];
  float e2 = (float)qkv[base + 64 + lane];
  float ss = e1 * e1 + e2 * e2;
#pragma unroll
  for (int m = 1; m < 64; m <<= 1) ss += __shfl_xor(ss, m);
  float inv = rsqrtf(ss * (1.0f / 128.0f) + 1.1920929e-7f);
  e1 *= inv; e2 *= inv;
  float invfreq = powf(10000.0f, -(float)lane * (1.0f / 64.0f));
  float ang = (float)s * invfreq;
  float sn, cs;
  sincosf(ang, &sn, &cs);
  float o1 = e1 * cs + e2 * sn;
  float o2 = -e1 * sn + e2 * cs;
  if (j < kH) { float g = qgain[j]; o1 *= g; o2 *= g; }
  qkv[base + lane] = (bf)o1;
  qkv[base + 64 + lane] = (bf)o2;
}

// ---------------- causal flash attention ----------------
// block: 128 q rows of one (b,h); 4 waves, each 32 q rows. KV tiles of 64.
__global__ __launch_bounds__(256) void attn_kernel(const bf* __restrict__ qkv,
                                                   bf* __restrict__ y,
                                                   const float* __restrict__ qgain) {
  __shared__ bf Ks[64 * 128];     // swizzled 256B rows
  __shared__ bf Vt[128 * 72];     // V transposed: row=d (stride 72 keeps 16B align, ~2-way)
  __shared__ bf Ps[4][32 * 64];   // per-wave P, swizzled 128B rows
  const int tid = threadIdx.x;
  const int w = tid >> 6, lane = tid & 63;
  const int r16 = lane & 15, kg = lane >> 4;
  const int qt = blockIdx.x;              // 0..15
  const int bh = blockIdx.y;              // 0..31
  const int b = bh >> 4, h = bh & 15, kvh = h >> 2;
  const size_t rowbase = (size_t)b * kS;
  const float scale = 0.08838834764831845f;   // 1/sqrt(128); q_gain already applied

  // Q fragments in registers (A-operand: row=lane&15, k = kg*8..+8)
  bf16x8 qf[2][4];
#pragma unroll
  for (int m = 0; m < 2; m++)
#pragma unroll
    for (int ks = 0; ks < 4; ks++) {
      int s = qt * 128 + w * 32 + m * 16 + r16;
      qf[m][ks] = *reinterpret_cast<const bf16x8*>(
          qkv + (rowbase + s) * kQKVN + h * kHd + ks * 32 + kg * 8);
    }

  f32x4 o[2][8] = {};
  float mrun[2][4], lrun[2][4];
#pragma unroll
  for (int m = 0; m < 2; m++)
#pragma unroll
    for (int r = 0; r < 4; r++) { mrun[m][r] = -1e30f; lrun[m][r] = 0.f; }

  const int nkv = 2 * (qt + 1);
  for (int kt = 0; kt < nkv; kt++) {
    __syncthreads();
    // stage K (global_load_lds, pre-swizzled source)
#pragma unroll
    for (int r = 0; r < 4; r++) {
      int u = r * 256 + tid;                        // 16 units per 256B row
      int krow = u >> 4;
      int cb = ((u & 15) * 16) ^ ((krow & 7) << 4);
      gload_lds16(qkv + (rowbase + kt * 64 + krow) * kQKVN + kD + kvh * kHd + (cb >> 1),
                  Ks + (size_t)(r * 256 + w * 64) * 8);
    }
    // stage V transposed (reg route)
#pragma unroll
    for (int r = 0; r < 4; r++) {
      int u = r * 256 + tid;
      int vrow = u >> 4;
      int d0 = (u & 15) * 8;
      bf16x8 vv = *reinterpret_cast<const bf16x8*>(
          qkv + (rowbase + kt * 64 + vrow) * kQKVN + kD + kKV * kHd + kvh * kHd + d0);
#pragma unroll
      for (int jj = 0; jj < 8; jj++) Vt[(d0 + jj) * 72 + vrow] = vv[jj];
    }
    __syncthreads();

    // S = Q K^T (per wave: 32q x 64k)
    f32x4 sf[2][4];
#pragma unroll
    for (int n = 0; n < 4; n++) {
      bf16x8 kf[4];
#pragma unroll
      for (int ks = 0; ks < 4; ks++) {
        int krow = n * 16 + r16;
        kf[ks] = *reinterpret_cast<const bf16x8*>(
            reinterpret_cast<const char*>(Ks) + krow * 256 +
            ((ks * 64 + kg * 16) ^ ((krow & 7) << 4)));
      }
#pragma unroll
      for (int m = 0; m < 2; m++) {
        f32x4 a = {};
#pragma unroll
        for (int ks = 0; ks < 4; ks++) a = mfma16(qf[m][ks], kf[ks], a);
        sf[m][n] = a;
      }
    }

    // scale + causal mask + online softmax + P write
#pragma unroll
    for (int m = 0; m < 2; m++) {
      float rmax[4] = {-1e30f, -1e30f, -1e30f, -1e30f};
#pragma unroll
      for (int n = 0; n < 4; n++) {
        int col = kt * 64 + n * 16 + r16;
#pragma unroll
        for (int r = 0; r < 4; r++) {
          int qrow = qt * 128 + w * 32 + m * 16 + kg * 4 + r;
          float sv = sf[m][n][r] * scale;
          sv = (col <= qrow) ? sv : -1e30f;
          sf[m][n][r] = sv;
          rmax[r] = fmaxf(rmax[r], sv);
        }
      }
#pragma unroll
      for (int r = 0; r < 4; r++) {
        rmax[r] = fmaxf(rmax[r], __shfl_xor(rmax[r], 1));
        rmax[r] = fmaxf(rmax[r], __shfl_xor(rmax[r], 2));
        rmax[r] = fmaxf(rmax[r], __shfl_xor(rmax[r], 4));
        rmax[r] = fmaxf(rmax[r], __shfl_xor(rmax[r], 8));
      }
      float resc[4], rsum[4];
#pragma unroll
      for (int r = 0; r < 4; r++) {
        float mnew = fmaxf(mrun[m][r], rmax[r]);
        resc[r] = __expf(mrun[m][r] - mnew);
        mrun[m][r] = mnew;
        rsum[r] = 0.f;
      }
#pragma unroll
      for (int n = 0; n < 4; n++)
#pragma unroll
        for (int r = 0; r < 4; r++) {
          float p = __expf(sf[m][n][r] - mrun[m][r]);
          sf[m][n][r] = p;
          rsum[r] += p;
        }
#pragma unroll
      for (int r = 0; r < 4; r++) {
        rsum[r] += __shfl_xor(rsum[r], 1);
        rsum[r] += __shfl_xor(rsum[r], 2);
        rsum[r] += __shfl_xor(rsum[r], 4);
        rsum[r] += __shfl_xor(rsum[r], 8);
        lrun[m][r] = lrun[m][r] * resc[r] + rsum[r];
      }
#pragma unroll
      for (int nf = 0; nf < 8; nf++)
#pragma unroll
        for (int r = 0; r < 4; r++) o[m][nf][r] *= resc[r];
      // write P (bf16) into per-wave swizzled LDS
      bf* pw = Ps[w];
#pragma unroll
      for (int n = 0; n < 4; n++) {
        int col2 = (n * 16 + r16) * 2;
#pragma unroll
        for (int r = 0; r < 4; r++) {
          int prow = m * 16 + kg * 4 + r;
          *reinterpret_cast<bf*>(reinterpret_cast<char*>(pw) + prow * 128 +
                                 (col2 ^ ((prow & 7) << 4))) = (bf)sf[m][n][r];
        }
      }
    }
    asm volatile("s_waitcnt lgkmcnt(0)" ::: "memory");
    __builtin_amdgcn_sched_barrier(0);

    // O += P V   (A = P from LDS, B = Vt rows = d)
    const bf* pw = Ps[w];
#pragma unroll
    for (int ksv = 0; ksv < 2; ksv++) {
      bf16x8 pa[2];
#pragma unroll
      for (int m = 0; m < 2; m++) {
        int prow = m * 16 + r16;
        pa[m] = *reinterpret_cast<const bf16x8*>(
            reinterpret_cast<const char*>(pw) + prow * 128 +
            ((ksv * 64 + kg * 16) ^ ((prow & 7) << 4)));
      }
#pragma unroll
      for (int nf = 0; nf < 8; nf++) {
        int vrow = nf * 16 + r16;
        bf16x8 vb = *reinterpret_cast<const bf16x8*>(Vt + vrow * 72 + ksv * 32 + kg * 8);
#pragma unroll
        for (int m = 0; m < 2; m++) o[m][nf] = mfma16(pa[m], vb, o[m][nf]);
      }
    }
  }

  // epilogue: O /= l, store to y (b,s,h,d)
#pragma unroll
  for (int m = 0; m < 2; m++) {
    float inv[4];
#pragma unroll
    for (int r = 0; r < 4; r++) inv[r] = 1.0f / lrun[m][r];
#pragma unroll
    for (int nf = 0; nf < 8; nf++)
#pragma unroll
      for (int r = 0; r < 4; r++) {
        int s = qt * 128 + w * 32 + m * 16 + kg * 4 + r;
        int d = nf * 16 + r16;
        y[(rowbase + s) * kD + h * kHd + d] = (bf)(o[m][nf][r] * inv[r]);
      }
  }
}

}  // namespace

extern "C" void kernel_launch(void* const* d_in, const int* in_sizes, int n_in,
                              void* d_out, int out_size, void* d_ws, size_t ws_size,
                              hipStream_t stream) {
  const float* x  = (const float*)d_in[0];
  const float* Wq = (const float*)d_in[1];
  const float* Wk = (const float*)d_in[2];
  const float* Wv = (const float*)d_in[3];
  const float* Wp = (const float*)d_in[4];
  const float* qg = (const float*)d_in[5];

  // workspace layout (bf16), total ~76 MiB
  bf* xb    = (bf*)d_ws;                       // 4096*2048
  bf* wqkvb = xb + (size_t)kM * kD;            // 3072*2048 (Wq|Wk|Wv rows)
  bf* wpb   = wqkvb + (size_t)kQKVN * kD;      // 2048*2048
  bf* qkv   = wpb + (size_t)kD * kD;           // 4096*3072
  bf* yb    = qkv + (size_t)kM * kQKVN;        // 4096*2048

  cvt_kernel<<<(kM * kD / 4) / 256, 256, 0, stream>>>(x, xb, kM * kD / 4);
  cvt_kernel<<<(kD * kD / 4) / 256, 256, 0, stream>>>(Wq, wqkvb, kD * kD / 4);
  cvt_kernel<<<(512 * kD / 4) / 256, 256, 0, stream>>>(Wk, wqkvb + (size_t)kD * kD, 512 * kD / 4);
  cvt_kernel<<<(512 * kD / 4) / 256, 256, 0, stream>>>(Wv, wqkvb + (size_t)kD * kD + (size_t)512 * kD, 512 * kD / 4);
  cvt_kernel<<<(kD * kD / 4) / 256, 256, 0, stream>>>(Wp, wpb, kD * kD / 4);

  // qkv = x @ [Wq;Wk;Wv]^T   (M=4096, N=3072, K=2048)
  gemm_bt<bf><<<dim3(kQKVN / 128, kM / 128), 256, 0, stream>>>(xb, kD, wqkvb, kD, qkv, kQKVN, kD);

  // RMSNorm + RoPE + gain in place
  normrope<<<(kB * kS * (kH + kKV)) / 4, 256, 0, stream>>>(qkv, qg);

  // flash attention -> yb
  attn_kernel<<<dim3(kS / 128, kB * kH), 256, 0, stream>>>(qkv, yb, qg);

  // out = yb @ Wproj^T  (M=4096, N=2048, K=2048) -> fp32 d_out
  gemm_bt<float><<<dim3(kD / 128, kM / 128), 256, 0, stream>>>(yb, kD, wpb, kD, (float*)d_out, kD, kD);
}

// Round 2
// 281.863 us; speedup vs baseline: 1.6418x; 1.6418x over previous
//
#include <hip/hip_runtime.h>
#include <hip/hip_bf16.h>
#include <stdint.h>

namespace {

constexpr int kB = 2;
constexpr int kS = 2048;
constexpr int kD = 2048;
constexpr int kH = 16;
constexpr int kKV = 4;
constexpr int kHd = 128;
constexpr int kM = kB * kS;      // 4096 token rows
constexpr int kQKN = kD + kKV * kHd; // 2560 (q cols 0..2047, k cols 2048..2559)

using bf = __bf16;
typedef bf bf16x8 __attribute__((ext_vector_type(8)));
typedef float f32x4 __attribute__((ext_vector_type(4)));

__device__ __forceinline__ f32x4 mfma16(bf16x8 a, bf16x8 b, f32x4 c) {
  return __builtin_amdgcn_mfma_f32_16x16x32_bf16(a, b, c, 0, 0, 0);
}

__device__ __forceinline__ void gload_lds16(const bf* g, bf* l) {
  __builtin_amdgcn_global_load_lds(
      (const __attribute__((address_space(1))) void*)(uintptr_t)g,
      (__attribute__((address_space(3))) void*)l, 16, 0, 0);
}

// ---------------- fp32 -> bf16 convert ----------------
__global__ __launch_bounds__(256) void cvt_kernel(const float* __restrict__ src,
                                                  bf* __restrict__ dst, int n4) {
  int i = blockIdx.x * 256 + threadIdx.x;
  if (i >= n4) return;
  float4 v = reinterpret_cast<const float4*>(src)[i];
  union { bf h[4]; uint2 u; } o;
  o.h[0] = (bf)v.x; o.h[1] = (bf)v.y; o.h[2] = (bf)v.z; o.h[3] = (bf)v.w;
  reinterpret_cast<uint2*>(dst)[i] = o.u;
}

// ---------------- C = A * B^T  (A[M][K], B[N][K], both K-contig bf16) ----------------
template <typename CT>
__global__ __launch_bounds__(256) void gemm_bt(const bf* __restrict__ A, int lda,
                                               const bf* __restrict__ Bm, int ldb,
                                               CT* __restrict__ C, int ldc, int K) {
  __shared__ bf As[128 * 64];
  __shared__ bf Bs[128 * 64];
  const int tid = threadIdx.x;
  const int w = tid >> 6, lane = tid & 63;
  const int r16 = lane & 15, kg = lane >> 4;
  const int bm = blockIdx.y * 128, bn = blockIdx.x * 128;
  const int wy = (w >> 1) * 64, wx = (w & 1) * 64;
  f32x4 acc[4][4] = {};
  for (int kt = 0; kt < K; kt += 64) {
    __syncthreads();
#pragma unroll
    for (int r = 0; r < 4; r++) {
      int u = r * 256 + tid;                       // 16B unit, 8 per 128B row
      int row = u >> 3;
      int cb = ((u & 7) * 16) ^ ((row & 7) << 4);  // pre-swizzle the SOURCE
      gload_lds16(A + (size_t)(bm + row) * lda + kt + (cb >> 1),
                  As + (size_t)(r * 256 + w * 64) * 8);
      gload_lds16(Bm + (size_t)(bn + row) * ldb + kt + (cb >> 1),
                  Bs + (size_t)(r * 256 + w * 64) * 8);
    }
    __syncthreads();
#pragma unroll
    for (int ks = 0; ks < 2; ks++) {
      bf16x8 af[4], bfr[4];
#pragma unroll
      for (int m = 0; m < 4; m++) {
        int row = wy + m * 16 + r16;
        af[m] = *reinterpret_cast<const bf16x8*>(
            reinterpret_cast<const char*>(As) + row * 128 +
            ((ks * 64 + kg * 16) ^ ((row & 7) << 4)));
      }
#pragma unroll
      for (int n = 0; n < 4; n++) {
        int row = wx + n * 16 + r16;
        bfr[n] = *reinterpret_cast<const bf16x8*>(
            reinterpret_cast<const char*>(Bs) + row * 128 +
            ((ks * 64 + kg * 16) ^ ((row & 7) << 4)));
      }
#pragma unroll
      for (int m = 0; m < 4; m++)
#pragma unroll
        for (int n = 0; n < 4; n++)
          acc[m][n] = mfma16(af[m], bfr[n], acc[m][n]);
    }
  }
#pragma unroll
  for (int m = 0; m < 4; m++)
#pragma unroll
    for (int n = 0; n < 4; n++)
#pragma unroll
      for (int r = 0; r < 4; r++) {
        int row = bm + wy + m * 16 + kg * 4 + r;
        int col = bn + wx + n * 16 + r16;
        C[(size_t)row * ldc + col] = (CT)acc[m][n][r];
      }
}

// ---------------- RMSNorm + RoPE + q_gain, in place on qk buffer ----------------
__global__ __launch_bounds__(256) void normrope(bf* __restrict__ qk,
                                                const float* __restrict__ qgain) {
  const int tid = threadIdx.x;
  const int w = tid >> 6, lane = tid & 63;
  int v = blockIdx.x * 4 + w;             // 0 .. B*S*(H+KV)-1
  int b = v / (kS * (kH + kKV));
  int rem = v % (kS * (kH + kKV));
  int s = rem / (kH + kKV);
  int j = rem % (kH + kKV);               // 0..15 q heads, 16..19 kv heads
  int colbase = (j < kH) ? j * kHd : kD + (j - kH) * kHd;
  size_t base = (size_t)(b * kS + s) * kQKN + colbase;
  float e1 = (float)qk[base + lane];
  float e2 = (float)qk[base + 64 + lane];
  float ss = e1 * e1 + e2 * e2;
#pragma unroll
  for (int m = 1; m < 64; m <<= 1) ss += __shfl_xor(ss, m);
  float inv = rsqrtf(ss * (1.0f / 128.0f) + 1.1920929e-7f);
  e1 *= inv; e2 *= inv;
  float invfreq = powf(10000.0f, -(float)lane * (1.0f / 64.0f));
  float ang = (float)s * invfreq;
  float sn, cs;
  sincosf(ang, &sn, &cs);
  float o1 = e1 * cs + e2 * sn;
  float o2 = -e1 * sn + e2 * cs;
  if (j < kH) { float g = qgain[j]; o1 *= g; o2 *= g; }
  qk[base + lane] = (bf)o1;
  qk[base + 64 + lane] = (bf)o2;
}

// ---------------- causal flash attention ----------------
// block: 256 thr (4 waves), handles q-tile PAIR (i, 31-i) of 64 rows each ->
// every block does exactly 33 kv-tiles of 64. K and V^T staged via
// global_load_lds (pre-swizzled source), double-buffered, 1 barrier/tile.
__global__ __launch_bounds__(256) void attn_kernel(const bf* __restrict__ qk,
                                                   const bf* __restrict__ vt,
                                                   bf* __restrict__ y) {
  __shared__ bf Ks[2][64 * 128];   // [kv row][d], swizzled 256B rows
  __shared__ bf Vs[2][128 * 64];   // [d][kv], swizzled 128B rows
  __shared__ bf Ps[4][16 * 64];    // per-wave P, swizzled 128B rows
  const int tid = threadIdx.x;
  const int w = tid >> 6, lane = tid & 63;
  const int r16 = lane & 15, kg = lane >> 4;
  const int pairIdx = blockIdx.x;         // 0..15
  const int bh = blockIdx.y;              // 0..31
  const int b = bh >> 4, h = bh & 15, kvh = h >> 2;
  const size_t rowbase = (size_t)b * kS;
  const bf* kbase = qk + kD + kvh * kHd;                       // + row*kQKN
  const bf* vbase = vt + (size_t)(kvh * kHd) * kM + b * kS;    // + d*kM + s
  const float scale = 0.08838834764831845f;

  auto stage = [&](int buf, int kt) {
#pragma unroll
    for (int r = 0; r < 4; r++) {
      int u = r * 256 + tid;                        // 16 units / 256B K row
      int krow = u >> 4;
      int cb = ((u & 15) * 16) ^ ((krow & 7) << 4);
      gload_lds16(kbase + (rowbase + kt * 64 + krow) * kQKN + (cb >> 1),
                  Ks[buf] + (size_t)(r * 256 + w * 64) * 8);
    }
#pragma unroll
    for (int r = 0; r < 4; r++) {
      int u = r * 256 + tid;                        // 8 units / 128B V row
      int vrow = u >> 3;
      int cb = ((u & 7) * 16) ^ ((vrow & 7) << 4);
      gload_lds16(vbase + (size_t)vrow * kM + kt * 64 + (cb >> 1),
                  Vs[buf] + (size_t)(r * 256 + w * 64) * 8);
    }
  };

#pragma unroll 1
  for (int ph = 0; ph < 2; ph++) {
    const int qi = ph ? (31 - pairIdx) : pairIdx;   // q-tile index 0..31
    const int q0 = qi * 64;

    // Q fragments (A-operand: row=lane&15, k=kg*8..+8)
    bf16x8 qf[4];
#pragma unroll
    for (int ks = 0; ks < 4; ks++) {
      int s = q0 + w * 16 + r16;
      qf[ks] = *reinterpret_cast<const bf16x8*>(
          qk + (rowbase + s) * kQKN + h * kHd + ks * 32 + kg * 8);
    }

    f32x4 o[8] = {};
    float mrun[4], lrun[4];
#pragma unroll
    for (int r = 0; r < 4; r++) { mrun[r] = -1e30f; lrun[r] = 0.f; }

    __syncthreads();           // protect buffers from previous phase readers
    int cur = 0;
    stage(0, 0);

    for (int kt = 0; kt <= qi; kt++) {
      __syncthreads();         // implicit vmcnt(0) drain: buf[cur] ready
      if (kt < qi) stage(cur ^ 1, kt + 1);   // prefetch overlaps compute

      // S = Q K^T (wave: 16q x 64k)
      f32x4 sf[4];
#pragma unroll
      for (int n = 0; n < 4; n++) {
        bf16x8 kf[4];
#pragma unroll
        for (int ks = 0; ks < 4; ks++) {
          int krow = n * 16 + r16;
          kf[ks] = *reinterpret_cast<const bf16x8*>(
              reinterpret_cast<const char*>(Ks[cur]) + krow * 256 +
              ((ks * 64 + kg * 16) ^ ((krow & 7) << 4)));
        }
        f32x4 a = {};
#pragma unroll
        for (int ks = 0; ks < 4; ks++) a = mfma16(qf[ks], kf[ks], a);
        sf[n] = a;
      }

      // scale + causal mask + online softmax
      float rmax[4] = {-1e30f, -1e30f, -1e30f, -1e30f};
#pragma unroll
      for (int n = 0; n < 4; n++) {
        int col = kt * 64 + n * 16 + r16;
#pragma unroll
        for (int r = 0; r < 4; r++) {
          int qrow = q0 + w * 16 + kg * 4 + r;
          float sv = sf[n][r] * scale;
          sv = (col <= qrow) ? sv : -1e30f;
          sf[n][r] = sv;
          rmax[r] = fmaxf(rmax[r], sv);
        }
      }
#pragma unroll
      for (int r = 0; r < 4; r++) {
        rmax[r] = fmaxf(rmax[r], __shfl_xor(rmax[r], 1));
        rmax[r] = fmaxf(rmax[r], __shfl_xor(rmax[r], 2));
        rmax[r] = fmaxf(rmax[r], __shfl_xor(rmax[r], 4));
        rmax[r] = fmaxf(rmax[r], __shfl_xor(rmax[r], 8));
      }
      float resc[4], rsum[4];
#pragma unroll
      for (int r = 0; r < 4; r++) {
        float mnew = fmaxf(mrun[r], rmax[r]);
        resc[r] = __expf(mrun[r] - mnew);
        mrun[r] = mnew;
        rsum[r] = 0.f;
      }
#pragma unroll
      for (int n = 0; n < 4; n++)
#pragma unroll
        for (int r = 0; r < 4; r++) {
          float p = __expf(sf[n][r] - mrun[r]);
          sf[n][r] = p;
          rsum[r] += p;
        }
#pragma unroll
      for (int r = 0; r < 4; r++) {
        rsum[r] += __shfl_xor(rsum[r], 1);
        rsum[r] += __shfl_xor(rsum[r], 2);
        rsum[r] += __shfl_xor(rsum[r], 4);
        rsum[r] += __shfl_xor(rsum[r], 8);
        lrun[r] = lrun[r] * resc[r] + rsum[r];
      }
#pragma unroll
      for (int nf = 0; nf < 8; nf++)
#pragma unroll
        for (int r = 0; r < 4; r++) o[nf][r] *= resc[r];

      // write P (bf16) into per-wave swizzled LDS
      bf* pw = Ps[w];
#pragma unroll
      for (int n = 0; n < 4; n++) {
        int col2 = (n * 16 + r16) * 2;
#pragma unroll
        for (int r = 0; r < 4; r++) {
          int prow = kg * 4 + r;
          *reinterpret_cast<bf*>(reinterpret_cast<char*>(pw) + prow * 128 +
                                 (col2 ^ ((prow & 7) << 4))) = (bf)sf[n][r];
        }
      }
      asm volatile("s_waitcnt lgkmcnt(0)" ::: "memory");
      __builtin_amdgcn_sched_barrier(0);

      // O += P V   (A = P from LDS, B = Vs rows = d)
      const bf* pw2 = Ps[w];
#pragma unroll
      for (int ksv = 0; ksv < 2; ksv++) {
        bf16x8 pa = *reinterpret_cast<const bf16x8*>(
            reinterpret_cast<const char*>(pw2) + r16 * 128 +
            ((ksv * 64 + kg * 16) ^ ((r16 & 7) << 4)));
#pragma unroll
        for (int nf = 0; nf < 8; nf++) {
          int vrow = nf * 16 + r16;
          bf16x8 vb = *reinterpret_cast<const bf16x8*>(
              reinterpret_cast<const char*>(Vs[cur]) + vrow * 128 +
              ((ksv * 64 + kg * 16) ^ ((vrow & 7) << 4)));
          o[nf] = mfma16(pa, vb, o[nf]);
        }
      }
      cur ^= 1;
    }

    // epilogue: O /= l, store to y (b,s,h,d)
    float inv[4];
#pragma unroll
    for (int r = 0; r < 4; r++) inv[r] = 1.0f / lrun[r];
#pragma unroll
    for (int nf = 0; nf < 8; nf++)
#pragma unroll
      for (int r = 0; r < 4; r++) {
        int s = q0 + w * 16 + kg * 4 + r;
        int d = nf * 16 + r16;
        y[(rowbase + s) * kD + h * kHd + d] = (bf)(o[nf][r] * inv[r]);
      }
  }
}

}  // namespace

extern "C" void kernel_launch(void* const* d_in, const int* in_sizes, int n_in,
                              void* d_out, int out_size, void* d_ws, size_t ws_size,
                              hipStream_t stream) {
  const float* x  = (const float*)d_in[0];
  const float* Wq = (const float*)d_in[1];
  const float* Wk = (const float*)d_in[2];
  const float* Wv = (const float*)d_in[3];
  const float* Wp = (const float*)d_in[4];
  const float* qg = (const float*)d_in[5];

  // workspace layout (bf16)
  bf* xb    = (bf*)d_ws;                       // 4096*2048
  bf* wqkvb = xb + (size_t)kM * kD;            // 3072*2048 (Wq|Wk|Wv rows)
  bf* wpb   = wqkvb + (size_t)3072 * kD;       // 2048*2048
  bf* qkbuf = wpb + (size_t)kD * kD;           // 4096*2560
  bf* vtbuf = qkbuf + (size_t)kM * kQKN;       // 512*4096 (V^T: [kv d][token])
  bf* yb    = vtbuf + (size_t)512 * kM;        // 4096*2048

  cvt_kernel<<<(kM * kD / 4) / 256, 256, 0, stream>>>(x, xb, kM * kD / 4);
  cvt_kernel<<<(kD * kD / 4) / 256, 256, 0, stream>>>(Wq, wqkvb, kD * kD / 4);
  cvt_kernel<<<(512 * kD / 4) / 256, 256, 0, stream>>>(Wk, wqkvb + (size_t)kD * kD, 512 * kD / 4);
  cvt_kernel<<<(512 * kD / 4) / 256, 256, 0, stream>>>(Wv, wqkvb + (size_t)kD * kD + (size_t)512 * kD, 512 * kD / 4);
  cvt_kernel<<<(kD * kD / 4) / 256, 256, 0, stream>>>(Wp, wpb, kD * kD / 4);

  // qk = x @ [Wq;Wk]^T   (M=4096, N=2560, K=2048)
  gemm_bt<bf><<<dim3(kQKN / 128, kM / 128), 256, 0, stream>>>(xb, kD, wqkvb, kD, qkbuf, kQKN, kD);

  // V^T = Wv @ x^T       (M=512, N=4096, K=2048) -> vt[kv d][token]
  gemm_bt<bf><<<dim3(kM / 128, 512 / 128), 256, 0, stream>>>(
      wqkvb + (size_t)(kD + 512) * kD, kD, xb, kD, vtbuf, kM, kD);

  // RMSNorm + RoPE + gain in place on qk
  normrope<<<(kB * kS * (kH + kKV)) / 4, 256, 0, stream>>>(qkbuf, qg);

  // flash attention -> yb
  attn_kernel<<<dim3(16, kB * kH), 256, 0, stream>>>(qkbuf, vtbuf, yb);

  // out = yb @ Wproj^T  (M=4096, N=2048, K=2048) -> fp32 d_out
  gemm_bt<float><<<dim3(kD / 128, kM / 128), 256, 0, stream>>>(yb, kD, wpb, kD, (float*)d_out, kD, kD);
}

// Round 3
// 262.454 us; speedup vs baseline: 1.7633x; 1.0740x over previous
//
#include <hip/hip_runtime.h>
#include <hip/hip_bf16.h>
#include <stdint.h>

namespace {

constexpr int kB = 2;
constexpr int kS = 2048;
constexpr int kD = 2048;
constexpr int kH = 16;
constexpr int kKV = 4;
constexpr int kHd = 128;
constexpr int kM = kB * kS;      // 4096 token rows
constexpr int kQKN = kD + kKV * kHd; // 2560 (q cols 0..2047, k cols 2048..2559)

using bf = __bf16;
typedef bf bf16x8 __attribute__((ext_vector_type(8)));
typedef float f32x4 __attribute__((ext_vector_type(4)));

__device__ __forceinline__ f32x4 mfma16(bf16x8 a, bf16x8 b, f32x4 c) {
  return __builtin_amdgcn_mfma_f32_16x16x32_bf16(a, b, c, 0, 0, 0);
}

__device__ __forceinline__ void gload_lds16(const bf* g, bf* l) {
  __builtin_amdgcn_global_load_lds(
      (const __attribute__((address_space(1))) void*)(uintptr_t)g,
      (__attribute__((address_space(3))) void*)l, 16, 0, 0);
}

// ---------------- fp32 -> bf16 convert ----------------
__global__ __launch_bounds__(256) void cvt_kernel(const float* __restrict__ src,
                                                  bf* __restrict__ dst, int n4) {
  int i = blockIdx.x * 256 + threadIdx.x;
  if (i >= n4) return;
  float4 v = reinterpret_cast<const float4*>(src)[i];
  union { bf h[4]; uint2 u; } o;
  o.h[0] = (bf)v.x; o.h[1] = (bf)v.y; o.h[2] = (bf)v.z; o.h[3] = (bf)v.w;
  reinterpret_cast<uint2*>(dst)[i] = o.u;
}

// ---------------- C = A * B^T  (A[M][K], B[N][K], both K-contig bf16) ----------------
template <typename CT>
__global__ __launch_bounds__(256) void gemm_bt(const bf* __restrict__ A, int lda,
                                               const bf* __restrict__ Bm, int ldb,
                                               CT* __restrict__ C, int ldc, int K) {
  __shared__ bf As[128 * 64];
  __shared__ bf Bs[128 * 64];
  const int tid = threadIdx.x;
  const int w = tid >> 6, lane = tid & 63;
  const int r16 = lane & 15, kg = lane >> 4;
  const int bm = blockIdx.y * 128, bn = blockIdx.x * 128;
  const int wy = (w >> 1) * 64, wx = (w & 1) * 64;
  f32x4 acc[4][4] = {};
  for (int kt = 0; kt < K; kt += 64) {
    __syncthreads();
#pragma unroll
    for (int r = 0; r < 4; r++) {
      int u = r * 256 + tid;                       // 16B unit, 8 per 128B row
      int row = u >> 3;
      int cb = ((u & 7) * 16) ^ ((row & 7) << 4);  // pre-swizzle the SOURCE
      gload_lds16(A + (size_t)(bm + row) * lda + kt + (cb >> 1),
                  As + (size_t)(r * 256 + w * 64) * 8);
      gload_lds16(Bm + (size_t)(bn + row) * ldb + kt + (cb >> 1),
                  Bs + (size_t)(r * 256 + w * 64) * 8);
    }
    __syncthreads();
#pragma unroll
    for (int ks = 0; ks < 2; ks++) {
      bf16x8 af[4], bfr[4];
#pragma unroll
      for (int m = 0; m < 4; m++) {
        int row = wy + m * 16 + r16;
        af[m] = *reinterpret_cast<const bf16x8*>(
            reinterpret_cast<const char*>(As) + row * 128 +
            ((ks * 64 + kg * 16) ^ ((row & 7) << 4)));
      }
#pragma unroll
      for (int n = 0; n < 4; n++) {
        int row = wx + n * 16 + r16;
        bfr[n] = *reinterpret_cast<const bf16x8*>(
            reinterpret_cast<const char*>(Bs) + row * 128 +
            ((ks * 64 + kg * 16) ^ ((row & 7) << 4)));
      }
#pragma unroll
      for (int m = 0; m < 4; m++)
#pragma unroll
        for (int n = 0; n < 4; n++)
          acc[m][n] = mfma16(af[m], bfr[n], acc[m][n]);
    }
  }
#pragma unroll
  for (int m = 0; m < 4; m++)
#pragma unroll
    for (int n = 0; n < 4; n++)
#pragma unroll
      for (int r = 0; r < 4; r++) {
        int row = bm + wy + m * 16 + kg * 4 + r;
        int col = bn + wx + n * 16 + r16;
        C[(size_t)row * ldc + col] = (CT)acc[m][n][r];
      }
}

// ---------------- RMSNorm + RoPE + gain, in place on qk buffer ----------------
// Q rows additionally scaled by 1/sqrt(hd)*log2(e) so attention softmax can
// run in exp2 domain with no per-element scale.
__global__ __launch_bounds__(256) void normrope(bf* __restrict__ qk,
                                                const float* __restrict__ qgain) {
  const int tid = threadIdx.x;
  const int w = tid >> 6, lane = tid & 63;
  int v = blockIdx.x * 4 + w;             // 0 .. B*S*(H+KV)-1
  int b = v / (kS * (kH + kKV));
  int rem = v % (kS * (kH + kKV));
  int s = rem / (kH + kKV);
  int j = rem % (kH + kKV);               // 0..15 q heads, 16..19 kv heads
  int colbase = (j < kH) ? j * kHd : kD + (j - kH) * kHd;
  size_t base = (size_t)(b * kS + s) * kQKN + colbase;
  float e1 = (float)qk[base + lane];
  float e2 = (float)qk[base + 64 + lane];
  float ss = e1 * e1 + e2 * e2;
#pragma unroll
  for (int m = 1; m < 64; m <<= 1) ss += __shfl_xor(ss, m);
  float inv = rsqrtf(ss * (1.0f / 128.0f) + 1.1920929e-7f);
  e1 *= inv; e2 *= inv;
  float invfreq = powf(10000.0f, -(float)lane * (1.0f / 64.0f));
  float ang = (float)s * invfreq;
  float sn, cs;
  sincosf(ang, &sn, &cs);
  float o1 = e1 * cs + e2 * sn;
  float o2 = -e1 * sn + e2 * cs;
  if (j < kH) {
    // fold q_gain * (1/sqrt(128)) * log2(e)
    float g = qgain[j] * (0.08838834764831845f * 1.4426950408889634f);
    o1 *= g; o2 *= g;
  }
  qk[base + lane] = (bf)o1;
  qk[base + 64 + lane] = (bf)o2;
}

// ---------------- causal flash attention ----------------
// 4 waves/block, q-tile PAIR (i, 31-i) of 64 rows -> 33 kv-tiles per block.
// Swapped QK^T (mfma(K,Q)) => per-lane q=r16 scalar softmax state; exp2
// domain (scale folded into q); defer-max rescale (THR=8); packed b64 P writes.
__global__ __launch_bounds__(256) void attn_kernel(const bf* __restrict__ qk,
                                                   const bf* __restrict__ vt,
                                                   bf* __restrict__ y) {
  __shared__ bf Ks[2][64 * 128];   // [kv row][d], swizzled 256B rows
  __shared__ bf Vs[2][128 * 64];   // [d][kv], swizzled 128B rows
  __shared__ bf Ps[4][16 * 64];    // per-wave P [q][k], swizzled 128B rows
  const int tid = threadIdx.x;
  const int w = tid >> 6, lane = tid & 63;
  const int r16 = lane & 15, kg = lane >> 4;
  const int pairIdx = blockIdx.x;         // 0..15
  const int bh = blockIdx.y;              // 0..31
  const int b = bh >> 4, h = bh & 15, kvh = h >> 2;
  const size_t rowbase = (size_t)b * kS;
  const bf* kbase = qk + kD + kvh * kHd;                       // + row*kQKN
  const bf* vbase = vt + (size_t)(kvh * kHd) * kM + b * kS;    // + d*kM + s

  auto stage = [&](int buf, int kt) {
#pragma unroll
    for (int r = 0; r < 4; r++) {
      int u = r * 256 + tid;                        // 16 units / 256B K row
      int krow = u >> 4;
      int cb = ((u & 15) * 16) ^ ((krow & 7) << 4);
      gload_lds16(kbase + (rowbase + kt * 64 + krow) * kQKN + (cb >> 1),
                  Ks[buf] + (size_t)(r * 256 + w * 64) * 8);
    }
#pragma unroll
    for (int r = 0; r < 4; r++) {
      int u = r * 256 + tid;                        // 8 units / 128B V row
      int vrow = u >> 3;
      int cb = ((u & 7) * 16) ^ ((vrow & 7) << 4);
      gload_lds16(vbase + (size_t)vrow * kM + kt * 64 + (cb >> 1),
                  Vs[buf] + (size_t)(r * 256 + w * 64) * 8);
    }
  };

#pragma unroll 1
  for (int ph = 0; ph < 2; ph++) {
    const int qi = ph ? (31 - pairIdx) : pairIdx;   // q-tile index 0..31
    const int q0 = qi * 64;
    const int qw = q0 + w * 16;          // this wave's q-row block base
    const int qrow = qw + r16;           // this lane's q row (swapped layout)

    // Q fragments (B-operand: row=r16 -> q, k=kg*8..+8)
    bf16x8 qf[4];
#pragma unroll
    for (int ks = 0; ks < 4; ks++) {
      qf[ks] = *reinterpret_cast<const bf16x8*>(
          qk + (rowbase + qrow) * kQKN + h * kHd + ks * 32 + kg * 8);
    }

    f32x4 o[8] = {};
    float mrun = -1e30f, lrun = 0.f;

    __syncthreads();           // protect buffers from previous phase readers
    int cur = 0;
    stage(0, 0);

    for (int kt = 0; kt <= qi; kt++) {
      __syncthreads();         // implicit vmcnt(0) drain: buf[cur] ready
      if (kt < qi) stage(cur ^ 1, kt + 1);   // prefetch overlaps compute

      // S^T tile via swapped mfma(K, Q): sf[n] rows = k_local, col = q = r16
      f32x4 sf[4];
      __builtin_amdgcn_s_setprio(1);
#pragma unroll
      for (int n = 0; n < 4; n++) {
        bf16x8 kf[4];
#pragma unroll
        for (int ks = 0; ks < 4; ks++) {
          int krow = n * 16 + r16;
          kf[ks] = *reinterpret_cast<const bf16x8*>(
              reinterpret_cast<const char*>(Ks[cur]) + krow * 256 +
              ((ks * 64 + kg * 16) ^ ((krow & 7) << 4)));
        }
        f32x4 a = {};
#pragma unroll
        for (int ks = 0; ks < 4; ks++) a = mfma16(kf[ks], qf[ks], a);
        sf[n] = a;
      }
      __builtin_amdgcn_s_setprio(0);

      // causal mask (skip when tile fully below diagonal — wave-uniform)
      if (kt * 64 + 63 > qw) {
#pragma unroll
        for (int n = 0; n < 4; n++)
#pragma unroll
          for (int r = 0; r < 4; r++) {
            int col = kt * 64 + n * 16 + kg * 4 + r;
            sf[n][r] = (col <= qrow) ? sf[n][r] : -1e30f;
          }
      }

      // per-lane row max (q fixed = r16)
      float rmax = sf[0][0];
#pragma unroll
      for (int n = 0; n < 4; n++)
#pragma unroll
        for (int r = 0; r < 4; r++) rmax = fmaxf(rmax, sf[n][r]);
      rmax = fmaxf(rmax, __shfl_xor(rmax, 16));
      rmax = fmaxf(rmax, __shfl_xor(rmax, 32));

      // defer-max: only rescale when the max grew materially (THR=8 in log2)
      if (!__all(rmax <= mrun + 8.0f)) {
        float mnew = fmaxf(mrun, rmax);
        float resc = exp2f(mrun - mnew);
        mrun = mnew;
        lrun *= resc;
        float rq[4];
#pragma unroll
        for (int r = 0; r < 4; r++) rq[r] = __shfl(resc, kg * 4 + r);
#pragma unroll
        for (int nf = 0; nf < 8; nf++)
#pragma unroll
          for (int r = 0; r < 4; r++) o[nf][r] *= rq[r];
      }

      // P = exp2(S - m), per-lane row sum
      float rsum = 0.f;
#pragma unroll
      for (int n = 0; n < 4; n++)
#pragma unroll
        for (int r = 0; r < 4; r++) {
          float p = exp2f(sf[n][r] - mrun);
          sf[n][r] = p;
          rsum += p;
        }
      rsum += __shfl_xor(rsum, 16);
      rsum += __shfl_xor(rsum, 32);
      lrun += rsum;

      // write P[q][k] — lane's 16 values all land in row q=r16: 4x ds_write_b64
      {
        char* prow = reinterpret_cast<char*>(Ps[w]) + r16 * 128;
#pragma unroll
        for (int n = 0; n < 4; n++) {
          union { bf h[4]; uint2 u2; } pk;
          pk.h[0] = (bf)sf[n][0]; pk.h[1] = (bf)sf[n][1];
          pk.h[2] = (bf)sf[n][2]; pk.h[3] = (bf)sf[n][3];
          *reinterpret_cast<uint2*>(prow + ((n * 32 + kg * 8) ^ ((r16 & 7) << 4))) = pk.u2;
        }
      }
      asm volatile("s_waitcnt lgkmcnt(0)" ::: "memory");
      __builtin_amdgcn_sched_barrier(0);

      // O += P V   (A = P from LDS rows q, B = Vs rows d)
      const bf* pw2 = Ps[w];
      __builtin_amdgcn_s_setprio(1);
#pragma unroll
      for (int ksv = 0; ksv < 2; ksv++) {
        bf16x8 pa = *reinterpret_cast<const bf16x8*>(
            reinterpret_cast<const char*>(pw2) + r16 * 128 +
            ((ksv * 64 + kg * 16) ^ ((r16 & 7) << 4)));
#pragma unroll
        for (int nf = 0; nf < 8; nf++) {
          int vrow = nf * 16 + r16;
          bf16x8 vb = *reinterpret_cast<const bf16x8*>(
              reinterpret_cast<const char*>(Vs[cur]) + vrow * 128 +
              ((ksv * 64 + kg * 16) ^ ((vrow & 7) << 4)));
          o[nf] = mfma16(pa, vb, o[nf]);
        }
      }
      __builtin_amdgcn_s_setprio(0);
      cur ^= 1;
    }

    // epilogue: O /= l (l redistributed to O rows), store to y (b,s,h,d)
    float linv = 1.0f / lrun;
    float lq[4];
#pragma unroll
    for (int r = 0; r < 4; r++) lq[r] = __shfl(linv, kg * 4 + r);
#pragma unroll
    for (int nf = 0; nf < 8; nf++)
#pragma unroll
      for (int r = 0; r < 4; r++) {
        int s = q0 + w * 16 + kg * 4 + r;
        int d = nf * 16 + r16;
        y[(rowbase + s) * kD + h * kHd + d] = (bf)(o[nf][r] * lq[r]);
      }
  }
}

}  // namespace

extern "C" void kernel_launch(void* const* d_in, const int* in_sizes, int n_in,
                              void* d_out, int out_size, void* d_ws, size_t ws_size,
                              hipStream_t stream) {
  const float* x  = (const float*)d_in[0];
  const float* Wq = (const float*)d_in[1];
  const float* Wk = (const float*)d_in[2];
  const float* Wv = (const float*)d_in[3];
  const float* Wp = (const float*)d_in[4];
  const float* qg = (const float*)d_in[5];

  // workspace layout (bf16)
  bf* xb    = (bf*)d_ws;                       // 4096*2048
  bf* wqkvb = xb + (size_t)kM * kD;            // 3072*2048 (Wq|Wk|Wv rows)
  bf* wpb   = wqkvb + (size_t)3072 * kD;       // 2048*2048
  bf* qkbuf = wpb + (size_t)kD * kD;           // 4096*2560
  bf* vtbuf = qkbuf + (size_t)kM * kQKN;       // 512*4096 (V^T: [kv d][token])
  bf* yb    = vtbuf + (size_t)512 * kM;        // 4096*2048

  cvt_kernel<<<(kM * kD / 4) / 256, 256, 0, stream>>>(x, xb, kM * kD / 4);
  cvt_kernel<<<(kD * kD / 4) / 256, 256, 0, stream>>>(Wq, wqkvb, kD * kD / 4);
  cvt_kernel<<<(512 * kD / 4) / 256, 256, 0, stream>>>(Wk, wqkvb + (size_t)kD * kD, 512 * kD / 4);
  cvt_kernel<<<(512 * kD / 4) / 256, 256, 0, stream>>>(Wv, wqkvb + (size_t)kD * kD + (size_t)512 * kD, 512 * kD / 4);
  cvt_kernel<<<(kD * kD / 4) / 256, 256, 0, stream>>>(Wp, wpb, kD * kD / 4);

  // qk = x @ [Wq;Wk]^T   (M=4096, N=2560, K=2048)
  gemm_bt<bf><<<dim3(kQKN / 128, kM / 128), 256, 0, stream>>>(xb, kD, wqkvb, kD, qkbuf, kQKN, kD);

  // V^T = Wv @ x^T       (M=512, N=4096, K=2048) -> vt[kv d][token]
  gemm_bt<bf><<<dim3(kM / 128, 512 / 128), 256, 0, stream>>>(
      wqkvb + (size_t)(kD + 512) * kD, kD, xb, kD, vtbuf, kM, kD);

  // RMSNorm + RoPE + gain (q also pre-scaled for exp2-domain softmax)
  normrope<<<(kB * kS * (kH + kKV)) / 4, 256, 0, stream>>>(qkbuf, qg);

  // flash attention -> yb
  attn_kernel<<<dim3(16, kB * kH), 256, 0, stream>>>(qkbuf, vtbuf, yb);

  // out = yb @ Wproj^T  (M=4096, N=2048, K=2048) -> fp32 d_out
  gemm_bt<float><<<dim3(kD / 128, kM / 128), 256, 0, stream>>>(yb, kD, wpb, kD, (float*)d_out, kD, kD);
}

// Round 4
// 261.769 us; speedup vs baseline: 1.7679x; 1.0026x over previous
//
#include <hip/hip_runtime.h>
#include <hip/hip_bf16.h>
#include <stdint.h>

namespace {

constexpr int kB = 2;
constexpr int kS = 2048;
constexpr int kD = 2048;
constexpr int kH = 16;
constexpr int kKV = 4;
constexpr int kHd = 128;
constexpr int kM = kB * kS;      // 4096 token rows
constexpr int kQKN = kD + kKV * kHd; // 2560 (q cols 0..2047, k cols 2048..2559)

using bf = __bf16;
typedef bf bf16x8 __attribute__((ext_vector_type(8)));
typedef float f32x4 __attribute__((ext_vector_type(4)));
typedef float f32x16 __attribute__((ext_vector_type(16)));

__device__ __forceinline__ f32x4 mfma16(bf16x8 a, bf16x8 b, f32x4 c) {
  return __builtin_amdgcn_mfma_f32_16x16x32_bf16(a, b, c, 0, 0, 0);
}
__device__ __forceinline__ f32x16 mfma32(bf16x8 a, bf16x8 b, f32x16 c) {
  return __builtin_amdgcn_mfma_f32_32x32x16_bf16(a, b, c, 0, 0, 0);
}

__device__ __forceinline__ void gload_lds16(const bf* g, bf* l) {
  __builtin_amdgcn_global_load_lds(
      (const __attribute__((address_space(1))) void*)(uintptr_t)g,
      (__attribute__((address_space(3))) void*)l, 16, 0, 0);
}

// ---------------- fp32 -> bf16 convert ----------------
__global__ __launch_bounds__(256) void cvt_kernel(const float* __restrict__ src,
                                                  bf* __restrict__ dst, int n4) {
  int i = blockIdx.x * 256 + threadIdx.x;
  if (i >= n4) return;
  float4 v = reinterpret_cast<const float4*>(src)[i];
  union { bf h[4]; uint2 u; } o;
  o.h[0] = (bf)v.x; o.h[1] = (bf)v.y; o.h[2] = (bf)v.z; o.h[3] = (bf)v.w;
  reinterpret_cast<uint2*>(dst)[i] = o.u;
}

// ---------------- C = A * B^T  (A[M][K], B[N][K], both K-contig bf16) ----------------
template <typename CT>
__global__ __launch_bounds__(256) void gemm_bt(const bf* __restrict__ A, int lda,
                                               const bf* __restrict__ Bm, int ldb,
                                               CT* __restrict__ C, int ldc, int K) {
  __shared__ bf As[128 * 64];
  __shared__ bf Bs[128 * 64];
  const int tid = threadIdx.x;
  const int w = tid >> 6, lane = tid & 63;
  const int r16 = lane & 15, kg = lane >> 4;
  const int bm = blockIdx.y * 128, bn = blockIdx.x * 128;
  const int wy = (w >> 1) * 64, wx = (w & 1) * 64;
  f32x4 acc[4][4] = {};
  for (int kt = 0; kt < K; kt += 64) {
    __syncthreads();
#pragma unroll
    for (int r = 0; r < 4; r++) {
      int u = r * 256 + tid;                       // 16B unit, 8 per 128B row
      int row = u >> 3;
      int cb = ((u & 7) * 16) ^ ((row & 7) << 4);  // pre-swizzle the SOURCE
      gload_lds16(A + (size_t)(bm + row) * lda + kt + (cb >> 1),
                  As + (size_t)(r * 256 + w * 64) * 8);
      gload_lds16(Bm + (size_t)(bn + row) * ldb + kt + (cb >> 1),
                  Bs + (size_t)(r * 256 + w * 64) * 8);
    }
    __syncthreads();
#pragma unroll
    for (int ks = 0; ks < 2; ks++) {
      bf16x8 af[4], bfr[4];
#pragma unroll
      for (int m = 0; m < 4; m++) {
        int row = wy + m * 16 + r16;
        af[m] = *reinterpret_cast<const bf16x8*>(
            reinterpret_cast<const char*>(As) + row * 128 +
            ((ks * 64 + kg * 16) ^ ((row & 7) << 4)));
      }
#pragma unroll
      for (int n = 0; n < 4; n++) {
        int row = wx + n * 16 + r16;
        bfr[n] = *reinterpret_cast<const bf16x8*>(
            reinterpret_cast<const char*>(Bs) + row * 128 +
            ((ks * 64 + kg * 16) ^ ((row & 7) << 4)));
      }
#pragma unroll
      for (int m = 0; m < 4; m++)
#pragma unroll
        for (int n = 0; n < 4; n++)
          acc[m][n] = mfma16(af[m], bfr[n], acc[m][n]);
    }
  }
#pragma unroll
  for (int m = 0; m < 4; m++)
#pragma unroll
    for (int n = 0; n < 4; n++)
#pragma unroll
      for (int r = 0; r < 4; r++) {
        int row = bm + wy + m * 16 + kg * 4 + r;
        int col = bn + wx + n * 16 + r16;
        C[(size_t)row * ldc + col] = (CT)acc[m][n][r];
      }
}

// ---------------- RMSNorm + RoPE + gain, in place on qk buffer ----------------
__global__ __launch_bounds__(256) void normrope(bf* __restrict__ qk,
                                                const float* __restrict__ qgain) {
  const int tid = threadIdx.x;
  const int w = tid >> 6, lane = tid & 63;
  int v = blockIdx.x * 4 + w;             // 0 .. B*S*(H+KV)-1
  int b = v / (kS * (kH + kKV));
  int rem = v % (kS * (kH + kKV));
  int s = rem / (kH + kKV);
  int j = rem % (kH + kKV);               // 0..15 q heads, 16..19 kv heads
  int colbase = (j < kH) ? j * kHd : kD + (j - kH) * kHd;
  size_t base = (size_t)(b * kS + s) * kQKN + colbase;
  float e1 = (float)qk[base + lane];
  float e2 = (float)qk[base + 64 + lane];
  float ss = e1 * e1 + e2 * e2;
#pragma unroll
  for (int m = 1; m < 64; m <<= 1) ss += __shfl_xor(ss, m);
  float inv = rsqrtf(ss * (1.0f / 128.0f) + 1.1920929e-7f);
  e1 *= inv; e2 *= inv;
  float invfreq = powf(10000.0f, -(float)lane * (1.0f / 64.0f));
  float ang = (float)s * invfreq;
  float sn, cs;
  sincosf(ang, &sn, &cs);
  float o1 = e1 * cs + e2 * sn;
  float o2 = -e1 * sn + e2 * cs;
  if (j < kH) {
    // fold q_gain * (1/sqrt(128)) * log2(e)  -> exp2-domain softmax
    float g = qgain[j] * (0.08838834764831845f * 1.4426950408889634f);
    o1 *= g; o2 *= g;
  }
  qk[base + lane] = (bf)o1;
  qk[base + 64 + lane] = (bf)o2;
}

// ---------------- causal flash attention (32x32 MFMA, P in-register) ----------
// 4 waves/block, each wave owns 32 q rows (q-tile 128). KVBLK=64 double-buffered.
// Swapped QK^T: lane holds S^T[k][q=lane&31]; P->PV A-frags built in-register
// via v_cvt_pk_bf16_f32 + v_permlane32_swap_b32 (no P LDS round-trip).
__global__ __launch_bounds__(256, 2) void attn_kernel(const bf* __restrict__ qk,
                                                      const bf* __restrict__ vt,
                                                      bf* __restrict__ y) {
  __shared__ bf Ks[2][64 * 128];   // [kv][d], swizzled 256B rows
  __shared__ bf Vs[2][128 * 64];   // [d][kv], swizzled 128B rows
  const int tid = threadIdx.x;
  const int w = tid >> 6, lane = tid & 63;
  const int q32 = lane & 31, hi = lane >> 5;
  const int bh = blockIdx.x;              // 0..31
  const int jb = blockIdx.y;              // 0..15
  const int qi = (jb < 8) ? jb : 23 - jb; // co-resident pairs sum to 34 tiles
  const int b = bh >> 4, h = bh & 15, kvh = h >> 2;
  const size_t rowbase = (size_t)b * kS;
  const bf* kbase = qk + kD + kvh * kHd;                       // + row*kQKN
  const bf* vbase = vt + (size_t)(kvh * kHd) * kM + b * kS;    // + d*kM + s

  auto stage = [&](int buf, int kt) {
#pragma unroll
    for (int r = 0; r < 4; r++) {
      int u = r * 256 + tid;                        // 16 units / 256B K row
      int krow = u >> 4;
      int cb = ((u & 15) * 16) ^ ((krow & 7) << 4);
      gload_lds16(kbase + (rowbase + kt * 64 + krow) * kQKN + (cb >> 1),
                  Ks[buf] + (size_t)(r * 256 + w * 64) * 8);
    }
#pragma unroll
    for (int r = 0; r < 4; r++) {
      int u = r * 256 + tid;                        // 8 units / 128B V row
      int vrow = u >> 3;
      int cb = ((u & 7) * 16) ^ ((vrow & 7) << 4);
      gload_lds16(vbase + (size_t)vrow * kM + kt * 64 + (cb >> 1),
                  Vs[buf] + (size_t)(r * 256 + w * 64) * 8);
    }
  };

  const int q0 = qi * 128;
  const int qg0 = q0 + w * 32;             // wave's q base
  const int qrow = qg0 + q32;              // lane's q row

  // Q fragments (B-operand: col=q32, d = dc*16 + hi*8 + j)
  bf16x8 qf[8];
#pragma unroll
  for (int dc = 0; dc < 8; dc++)
    qf[dc] = *reinterpret_cast<const bf16x8*>(
        qk + (rowbase + qrow) * kQKN + h * kHd + dc * 16 + hi * 8);

  f32x16 o[4] = {};
  float mrun = -1e30f, lrun = 0.f;

  int cur = 0;
  stage(0, 0);
  const int ntiles = 2 * qi + 2;

  for (int kt = 0; kt < ntiles; kt++) {
    __syncthreads();           // implicit vmcnt(0): buf[cur] ready
    if (kt + 1 < ntiles) stage(cur ^ 1, kt + 1);   // prefetch overlaps compute

    if (kt * 64 <= qg0 + 31) {   // wave-uniform: skip fully-masked tiles
      // S^T[64k][32q] via swapped mfma(K, Q); sf[kb]: col=q32, row k = crow(r,hi)
      f32x16 sf[2];
      __builtin_amdgcn_s_setprio(1);
#pragma unroll
      for (int kb = 0; kb < 2; kb++) {
        f32x16 a = {};
#pragma unroll
        for (int dc = 0; dc < 8; dc++) {
          int krow = kb * 32 + q32;
          bf16x8 kf = *reinterpret_cast<const bf16x8*>(
              reinterpret_cast<const char*>(Ks[cur]) + krow * 256 +
              ((dc * 32 + hi * 16) ^ ((krow & 7) << 4)));
          a = mfma32(kf, qf[dc], a);
        }
        sf[kb] = a;
      }
      __builtin_amdgcn_s_setprio(0);

      // causal mask (only when tile straddles this wave's diagonal)
      if (kt * 64 + 63 > qg0) {
#pragma unroll
        for (int kb = 0; kb < 2; kb++)
#pragma unroll
          for (int r = 0; r < 16; r++) {
            int kgl = kt * 64 + kb * 32 + (r & 3) + 8 * (r >> 2) + 4 * hi;
            sf[kb][r] = (kgl <= qrow) ? sf[kb][r] : -1e30f;
          }
      }

      // row max (q = q32; partner hi-half holds the other 32 k's)
      float rmax = sf[0][0];
#pragma unroll
      for (int kb = 0; kb < 2; kb++)
#pragma unroll
        for (int r = 0; r < 16; r++) rmax = fmaxf(rmax, sf[kb][r]);
      rmax = fmaxf(rmax, __shfl_xor(rmax, 32));

      // defer-max rescale (THR=8 in log2 domain)
      if (!__all(rmax <= mrun + 8.0f)) {
        float mnew = fmaxf(mrun, rmax);
        float resc = exp2f(mrun - mnew);
        mrun = mnew;
        lrun *= resc;
        float rq[16];
#pragma unroll
        for (int r = 0; r < 16; r++)
          rq[r] = __shfl(resc, (r & 3) + 8 * (r >> 2) + 4 * hi);
#pragma unroll
        for (int db = 0; db < 4; db++)
#pragma unroll
          for (int r = 0; r < 16; r++) o[db][r] *= rq[r];
      }

      // P = exp2(S - m), row sum
      float rsum = 0.f;
#pragma unroll
      for (int kb = 0; kb < 2; kb++)
#pragma unroll
        for (int r = 0; r < 16; r++) {
          float p = exp2f(sf[kb][r] - mrun);
          sf[kb][r] = p;
          rsum += p;
        }
      rsum += __shfl_xor(rsum, 32);
      lrun += rsum;

      // Build PV A-frags in-register: 16 cvt_pk + 8 permlane32_swap.
      // pa[c] holds P[q=q32][k = c*16 + hi*8 + j], j=0..7.
      bf16x8 pa[4];
#pragma unroll
      for (int kb = 0; kb < 2; kb++) {
        uint32_t wa[4], wb[4];
#pragma unroll
        for (int g = 0; g < 4; g++) {
          asm("v_cvt_pk_bf16_f32 %0, %1, %2"
              : "=v"(wa[g]) : "v"(sf[kb][4 * g + 0]), "v"(sf[kb][4 * g + 1]));
          asm("v_cvt_pk_bf16_f32 %0, %1, %2"
              : "=v"(wb[g]) : "v"(sf[kb][4 * g + 2]), "v"(sf[kb][4 * g + 3]));
        }
        // swap(X,Y): X' = {X.lo, Y.lo}, Y' = {X.hi, Y.hi}
        asm volatile("v_permlane32_swap_b32 %0, %1" : "+v"(wa[0]), "+v"(wa[1]));
        asm volatile("v_permlane32_swap_b32 %0, %1" : "+v"(wb[0]), "+v"(wb[1]));
        asm volatile("v_permlane32_swap_b32 %0, %1" : "+v"(wa[2]), "+v"(wa[3]));
        asm volatile("v_permlane32_swap_b32 %0, %1" : "+v"(wb[2]), "+v"(wb[3]));
        union { uint32_t u[4]; bf16x8 v; } p0, p1;
        p0.u[0] = wa[0]; p0.u[1] = wb[0]; p0.u[2] = wa[1]; p0.u[3] = wb[1];
        p1.u[0] = wa[2]; p1.u[1] = wb[2]; p1.u[2] = wa[3]; p1.u[3] = wb[3];
        pa[2 * kb + 0] = p0.v;
        pa[2 * kb + 1] = p1.v;
      }

      // O += P V  (B = Vs rows d: col=q32 -> d, kv = c*16 + hi*8 + j)
      __builtin_amdgcn_s_setprio(1);
#pragma unroll
      for (int c = 0; c < 4; c++)
#pragma unroll
        for (int db = 0; db < 4; db++) {
          int vrow = db * 32 + q32;
          bf16x8 vb = *reinterpret_cast<const bf16x8*>(
              reinterpret_cast<const char*>(Vs[cur]) + vrow * 128 +
              ((c * 32 + hi * 16) ^ ((vrow & 7) << 4)));
          o[db] = mfma32(pa[c], vb, o[db]);
        }
      __builtin_amdgcn_s_setprio(0);
    }
    cur ^= 1;
  }

  // epilogue: O /= l, store to y (b,s,h,d)
  float linv = 1.0f / lrun;
  float lq[16];
#pragma unroll
  for (int r = 0; r < 16; r++)
    lq[r] = __shfl(linv, (r & 3) + 8 * (r >> 2) + 4 * hi);
#pragma unroll
  for (int db = 0; db < 4; db++)
#pragma unroll
    for (int r = 0; r < 16; r++) {
      int s = qg0 + (r & 3) + 8 * (r >> 2) + 4 * hi;
      int d = db * 32 + q32;
      y[(rowbase + s) * kD + h * kHd + d] = (bf)(o[db][r] * lq[r]);
    }
}

}  // namespace

extern "C" void kernel_launch(void* const* d_in, const int* in_sizes, int n_in,
                              void* d_out, int out_size, void* d_ws, size_t ws_size,
                              hipStream_t stream) {
  const float* x  = (const float*)d_in[0];
  const float* Wq = (const float*)d_in[1];
  const float* Wk = (const float*)d_in[2];
  const float* Wv = (const float*)d_in[3];
  const float* Wp = (const float*)d_in[4];
  const float* qg = (const float*)d_in[5];

  // workspace layout (bf16)
  bf* xb    = (bf*)d_ws;                       // 4096*2048
  bf* wqkvb = xb + (size_t)kM * kD;            // 3072*2048 (Wq|Wk|Wv rows)
  bf* wpb   = wqkvb + (size_t)3072 * kD;       // 2048*2048
  bf* qkbuf = wpb + (size_t)kD * kD;           // 4096*2560
  bf* vtbuf = qkbuf + (size_t)kM * kQKN;       // 512*4096 (V^T: [kv d][token])
  bf* yb    = vtbuf + (size_t)512 * kM;        // 4096*2048

  cvt_kernel<<<(kM * kD / 4) / 256, 256, 0, stream>>>(x, xb, kM * kD / 4);
  cvt_kernel<<<(kD * kD / 4) / 256, 256, 0, stream>>>(Wq, wqkvb, kD * kD / 4);
  cvt_kernel<<<(512 * kD / 4) / 256, 256, 0, stream>>>(Wk, wqkvb + (size_t)kD * kD, 512 * kD / 4);
  cvt_kernel<<<(512 * kD / 4) / 256, 256, 0, stream>>>(Wv, wqkvb + (size_t)kD * kD + (size_t)512 * kD, 512 * kD / 4);
  cvt_kernel<<<(kD * kD / 4) / 256, 256, 0, stream>>>(Wp, wpb, kD * kD / 4);

  // qk = x @ [Wq;Wk]^T   (M=4096, N=2560, K=2048)
  gemm_bt<bf><<<dim3(kQKN / 128, kM / 128), 256, 0, stream>>>(xb, kD, wqkvb, kD, qkbuf, kQKN, kD);

  // V^T = Wv @ x^T       (M=512, N=4096, K=2048) -> vt[kv d][token]
  gemm_bt<bf><<<dim3(kM / 128, 512 / 128), 256, 0, stream>>>(
      wqkvb + (size_t)(kD + 512) * kD, kD, xb, kD, vtbuf, kM, kD);

  // RMSNorm + RoPE + gain (q also pre-scaled for exp2-domain softmax)
  normrope<<<(kB * kS * (kH + kKV)) / 4, 256, 0, stream>>>(qkbuf, qg);

  // flash attention -> yb
  attn_kernel<<<dim3(kB * kH, 16), 256, 0, stream>>>(qkbuf, vtbuf, yb);

  // out = yb @ Wproj^T  (M=4096, N=2048, K=2048) -> fp32 d_out
  gemm_bt<float><<<dim3(kD / 128, kM / 128), 256, 0, stream>>>(yb, kD, wpb, kD, (float*)d_out, kD, kD);
}

// Round 5
// 251.282 us; speedup vs baseline: 1.8417x; 1.0417x over previous
//
#include <hip/hip_runtime.h>
#include <hip/hip_bf16.h>
#include <stdint.h>

namespace {

constexpr int kB = 2;
constexpr int kS = 2048;
constexpr int kD = 2048;
constexpr int kH = 16;
constexpr int kKV = 4;
constexpr int kHd = 128;
constexpr int kM = kB * kS;      // 4096 token rows
constexpr int kQKN = kD + kKV * kHd; // 2560 (q cols 0..2047, k cols 2048..2559)

using bf = __bf16;
typedef bf bf16x8 __attribute__((ext_vector_type(8)));
typedef float f32x4 __attribute__((ext_vector_type(4)));
typedef float f32x16 __attribute__((ext_vector_type(16)));

__device__ __forceinline__ f32x4 mfma16(bf16x8 a, bf16x8 b, f32x4 c) {
  return __builtin_amdgcn_mfma_f32_16x16x32_bf16(a, b, c, 0, 0, 0);
}
__device__ __forceinline__ f32x16 mfma32(bf16x8 a, bf16x8 b, f32x16 c) {
  return __builtin_amdgcn_mfma_f32_32x32x16_bf16(a, b, c, 0, 0, 0);
}

__device__ __forceinline__ void gload_lds16(const bf* g, bf* l) {
  __builtin_amdgcn_global_load_lds(
      (const __attribute__((address_space(1))) void*)(uintptr_t)g,
      (__attribute__((address_space(3))) void*)l, 16, 0, 0);
}

// ---------------- fp32 -> bf16 convert ----------------
__global__ __launch_bounds__(256) void cvt_kernel(const float* __restrict__ src,
                                                  bf* __restrict__ dst, int n4) {
  int i = blockIdx.x * 256 + threadIdx.x;
  if (i >= n4) return;
  float4 v = reinterpret_cast<const float4*>(src)[i];
  union { bf h[4]; uint2 u; } o;
  o.h[0] = (bf)v.x; o.h[1] = (bf)v.y; o.h[2] = (bf)v.z; o.h[3] = (bf)v.w;
  reinterpret_cast<uint2*>(dst)[i] = o.u;
}

// ---------------- C = A * B^T  (A[M][K], B[N][K], both K-contig bf16) ----------------
template <typename CT>
__global__ __launch_bounds__(256) void gemm_bt(const bf* __restrict__ A, int lda,
                                               const bf* __restrict__ Bm, int ldb,
                                               CT* __restrict__ C, int ldc, int K) {
  __shared__ bf As[128 * 64];
  __shared__ bf Bs[128 * 64];
  const int tid = threadIdx.x;
  const int w = tid >> 6, lane = tid & 63;
  const int r16 = lane & 15, kg = lane >> 4;
  const int bm = blockIdx.y * 128, bn = blockIdx.x * 128;
  const int wy = (w >> 1) * 64, wx = (w & 1) * 64;
  f32x4 acc[4][4] = {};
  for (int kt = 0; kt < K; kt += 64) {
    __syncthreads();
#pragma unroll
    for (int r = 0; r < 4; r++) {
      int u = r * 256 + tid;                       // 16B unit, 8 per 128B row
      int row = u >> 3;
      int cb = ((u & 7) * 16) ^ ((row & 7) << 4);  // pre-swizzle the SOURCE
      gload_lds16(A + (size_t)(bm + row) * lda + kt + (cb >> 1),
                  As + (size_t)(r * 256 + w * 64) * 8);
      gload_lds16(Bm + (size_t)(bn + row) * ldb + kt + (cb >> 1),
                  Bs + (size_t)(r * 256 + w * 64) * 8);
    }
    __syncthreads();
#pragma unroll
    for (int ks = 0; ks < 2; ks++) {
      bf16x8 af[4], bfr[4];
#pragma unroll
      for (int m = 0; m < 4; m++) {
        int row = wy + m * 16 + r16;
        af[m] = *reinterpret_cast<const bf16x8*>(
            reinterpret_cast<const char*>(As) + row * 128 +
            ((ks * 64 + kg * 16) ^ ((row & 7) << 4)));
      }
#pragma unroll
      for (int n = 0; n < 4; n++) {
        int row = wx + n * 16 + r16;
        bfr[n] = *reinterpret_cast<const bf16x8*>(
            reinterpret_cast<const char*>(Bs) + row * 128 +
            ((ks * 64 + kg * 16) ^ ((row & 7) << 4)));
      }
#pragma unroll
      for (int m = 0; m < 4; m++)
#pragma unroll
        for (int n = 0; n < 4; n++)
          acc[m][n] = mfma16(af[m], bfr[n], acc[m][n]);
    }
  }
#pragma unroll
  for (int m = 0; m < 4; m++)
#pragma unroll
    for (int n = 0; n < 4; n++)
#pragma unroll
      for (int r = 0; r < 4; r++) {
        int row = bm + wy + m * 16 + kg * 4 + r;
        int col = bn + wx + n * 16 + r16;
        C[(size_t)row * ldc + col] = (CT)acc[m][n][r];
      }
}

// ---------------- RMSNorm + RoPE + gain, in place on qk buffer ----------------
__global__ __launch_bounds__(256) void normrope(bf* __restrict__ qk,
                                                const float* __restrict__ qgain) {
  const int tid = threadIdx.x;
  const int w = tid >> 6, lane = tid & 63;
  int v = blockIdx.x * 4 + w;             // 0 .. B*S*(H+KV)-1
  int b = v / (kS * (kH + kKV));
  int rem = v % (kS * (kH + kKV));
  int s = rem / (kH + kKV);
  int j = rem % (kH + kKV);               // 0..15 q heads, 16..19 kv heads
  int colbase = (j < kH) ? j * kHd : kD + (j - kH) * kHd;
  size_t base = (size_t)(b * kS + s) * kQKN + colbase;
  float e1 = (float)qk[base + lane];
  float e2 = (float)qk[base + 64 + lane];
  float ss = e1 * e1 + e2 * e2;
#pragma unroll
  for (int m = 1; m < 64; m <<= 1) ss += __shfl_xor(ss, m);
  float inv = rsqrtf(ss * (1.0f / 128.0f) + 1.1920929e-7f);
  e1 *= inv; e2 *= inv;
  float invfreq = powf(10000.0f, -(float)lane * (1.0f / 64.0f));
  float ang = (float)s * invfreq;
  float sn, cs;
  sincosf(ang, &sn, &cs);
  float o1 = e1 * cs + e2 * sn;
  float o2 = -e1 * sn + e2 * cs;
  if (j < kH) {
    // fold q_gain * (1/sqrt(128)) * log2(e)  -> exp2-domain softmax
    float g = qgain[j] * (0.08838834764831845f * 1.4426950408889634f);
    o1 *= g; o2 *= g;
  }
  qk[base + lane] = (bf)o1;
  qk[base + 64 + lane] = (bf)o2;
}

// ---------------- causal flash attention (32x32 MFMA, P in-register) ----------
// Block = 4 waves. Wave = 32 q rows x 32 kv rows: qhalf = w&1, kvhalf = w>>1.
// Block covers a 64-row q-tile; two sequential phases (j, 31-j) => every block
// runs exactly 33 kv rounds (dispatch-order-proof balance). kv-half partial
// softmaxes merged exactly at phase end via LDS.
__global__ __launch_bounds__(256, 2) void attn_kernel(const bf* __restrict__ qk,
                                                      const bf* __restrict__ vt,
                                                      bf* __restrict__ y) {
  __shared__ bf Ks[2][64 * 128];   // [kv][d], swizzled 256B rows (32 KB)
  __shared__ bf Vs[2][128 * 64];   // [d][kv], swizzled 128B rows (32 KB)
  __shared__ float Ml[2][64][2];   // kv-half=1 waves' (m, l)
  const int tid = threadIdx.x;
  const int w = tid >> 6, lane = tid & 63;
  const int q32 = lane & 31, hi = lane >> 5;
  const int qhalf = w & 1, kvhalf = w >> 1;
  const int bh = blockIdx.x;              // 0..31
  const int pairIdx = blockIdx.y;         // 0..15
  const int b = bh >> 4, h = bh & 15, kvh = h >> 2;
  const size_t rowbase = (size_t)b * kS;
  const bf* kbase = qk + kD + kvh * kHd;                       // + row*kQKN
  const bf* vbase = vt + (size_t)(kvh * kHd) * kM + b * kS;    // + d*kM + s

  auto stage = [&](int buf, int kt) {
#pragma unroll
    for (int r = 0; r < 4; r++) {
      int u = r * 256 + tid;                        // 16 units / 256B K row
      int krow = u >> 4;
      int cb = ((u & 15) * 16) ^ ((krow & 7) << 4);
      gload_lds16(kbase + (rowbase + kt * 64 + krow) * kQKN + (cb >> 1),
                  Ks[buf] + (size_t)(r * 256 + w * 64) * 8);
    }
#pragma unroll
    for (int r = 0; r < 4; r++) {
      int u = r * 256 + tid;                        // 8 units / 128B V row
      int vrow = u >> 3;
      int cb = ((u & 7) * 16) ^ ((vrow & 7) << 4);
      gload_lds16(vbase + (size_t)vrow * kM + kt * 64 + (cb >> 1),
                  Vs[buf] + (size_t)(r * 256 + w * 64) * 8);
    }
  };

#pragma unroll 1
  for (int ph = 0; ph < 2; ph++) {
    const int j = ph ? (31 - pairIdx) : pairIdx;    // q-tile index 0..31
    const int q0 = j * 64;
    const int qg0 = q0 + qhalf * 32;                // wave's q base
    const int qrow = qg0 + q32;                     // lane's q row
    const int kvoff = kvhalf * 32;                  // wave's kv sub-block

    // Q fragments (B-operand: col=q32, k-dim d = dc*16 + hi*8 + jj)
    bf16x8 qf[8];
#pragma unroll
    for (int dc = 0; dc < 8; dc++)
      qf[dc] = *reinterpret_cast<const bf16x8*>(
          qk + (rowbase + qrow) * kQKN + h * kHd + dc * 16 + hi * 8);

    f32x16 o[4] = {};
    float mrun = -1e30f, lrun = 0.f;

    int cur = 0;
    stage(0, 0);

    for (int kt = 0; kt <= j; kt++) {
      __syncthreads();           // implicit vmcnt(0): buf[cur] ready
      if (kt < j) stage(cur ^ 1, kt + 1);   // prefetch overlaps compute

      if (kt * 64 + kvoff <= qg0 + 31) {    // wave-uniform skip
        // S^T[32kv][32q] via swapped mfma(K, Q): col=q32, row kv = crow(r,hi)
        f32x16 sf = {};
        __builtin_amdgcn_s_setprio(1);
#pragma unroll
        for (int dc = 0; dc < 8; dc++) {
          int krow = kvoff + q32;
          bf16x8 kf = *reinterpret_cast<const bf16x8*>(
              reinterpret_cast<const char*>(Ks[cur]) + krow * 256 +
              ((dc * 32 + hi * 16) ^ ((krow & 7) << 4)));
          sf = mfma32(kf, qf[dc], sf);
        }
        __builtin_amdgcn_s_setprio(0);

        // causal mask (only when the 32-kv strip straddles the diagonal)
        if (kt * 64 + kvoff + 31 > qg0) {
#pragma unroll
          for (int r = 0; r < 16; r++) {
            int kgl = kt * 64 + kvoff + (r & 3) + 8 * (r >> 2) + 4 * hi;
            sf[r] = (kgl <= qrow) ? sf[r] : -1e30f;
          }
        }

        // row max (q = q32; other hi-half holds the other 16 kv's)
        float rmax = sf[0];
#pragma unroll
        for (int r = 1; r < 16; r++) rmax = fmaxf(rmax, sf[r]);
        rmax = fmaxf(rmax, __shfl_xor(rmax, 32));

        // defer-max rescale (THR=8 in log2 domain)
        if (!__all(rmax <= mrun + 8.0f)) {
          float mnew = fmaxf(mrun, rmax);
          float resc = exp2f(mrun - mnew);
          mrun = mnew;
          lrun *= resc;
          float rq[16];
#pragma unroll
          for (int r = 0; r < 16; r++)
            rq[r] = __shfl(resc, (r & 3) + 8 * (r >> 2) + 4 * hi);
#pragma unroll
          for (int db = 0; db < 4; db++)
#pragma unroll
            for (int r = 0; r < 16; r++) o[db][r] *= rq[r];
        }

        // P = exp2(S - m), row sum
        float rsum = 0.f;
#pragma unroll
        for (int r = 0; r < 16; r++) {
          float p = exp2f(sf[r] - mrun);
          sf[r] = p;
          rsum += p;
        }
        rsum += __shfl_xor(rsum, 32);
        lrun += rsum;

        // PV A-frags in-register: 8 cvt_pk + 4 permlane32_swap.
        // pa[c] holds P[q=q32][kv_local = c*16 + hi*8 + jj]
        bf16x8 pa[2];
        {
          uint32_t wa[4], wb[4];
#pragma unroll
          for (int g = 0; g < 4; g++) {
            asm("v_cvt_pk_bf16_f32 %0, %1, %2"
                : "=v"(wa[g]) : "v"(sf[4 * g + 0]), "v"(sf[4 * g + 1]));
            asm("v_cvt_pk_bf16_f32 %0, %1, %2"
                : "=v"(wb[g]) : "v"(sf[4 * g + 2]), "v"(sf[4 * g + 3]));
          }
          asm volatile("v_permlane32_swap_b32 %0, %1" : "+v"(wa[0]), "+v"(wa[1]));
          asm volatile("v_permlane32_swap_b32 %0, %1" : "+v"(wb[0]), "+v"(wb[1]));
          asm volatile("v_permlane32_swap_b32 %0, %1" : "+v"(wa[2]), "+v"(wa[3]));
          asm volatile("v_permlane32_swap_b32 %0, %1" : "+v"(wb[2]), "+v"(wb[3]));
          union { uint32_t u[4]; bf16x8 v; } p0, p1;
          p0.u[0] = wa[0]; p0.u[1] = wb[0]; p0.u[2] = wa[1]; p0.u[3] = wb[1];
          p1.u[0] = wa[2]; p1.u[1] = wb[2]; p1.u[2] = wa[3]; p1.u[3] = wb[3];
          pa[0] = p0.v; pa[1] = p1.v;
        }

        // O += P V  (B = Vs rows d: col=q32 -> d; kv byte = kvoff*2 + c*32 + hi*16)
        __builtin_amdgcn_s_setprio(1);
#pragma unroll
        for (int c = 0; c < 2; c++)
#pragma unroll
          for (int db = 0; db < 4; db++) {
            int vrow = db * 32 + q32;
            bf16x8 vb = *reinterpret_cast<const bf16x8*>(
                reinterpret_cast<const char*>(Vs[cur]) + vrow * 128 +
                ((kvhalf * 64 + c * 32 + hi * 16) ^ ((vrow & 7) << 4)));
            o[db] = mfma32(pa[c], vb, o[db]);
          }
        __builtin_amdgcn_s_setprio(0);
      }
      cur ^= 1;
    }

    // ---- exact merge of the two kv-half partials, then store ----
    __syncthreads();                       // all PV reads of Ks/Vs done
    float* mb = reinterpret_cast<float*>(Ks);   // 32 KB = 8192 floats, reused
    if (w >= 2) {
      Ml[w - 2][lane][0] = mrun;
      Ml[w - 2][lane][1] = lrun;
      int base = (w - 2) * 4096;
#pragma unroll
      for (int db = 0; db < 4; db++)
#pragma unroll
        for (int r = 0; r < 16; r++)
          mb[base + (db * 16 + r) * 64 + lane] = o[db][r];
    }
    __syncthreads();                       // partials visible
    if (w < 2) {
      float m1 = Ml[w][lane][0], l1 = Ml[w][lane][1];
      float m = fmaxf(mrun, m1);
      float f0 = exp2f(mrun - m), f1 = exp2f(m1 - m);
      float linv = 1.0f / (lrun * f0 + l1 * f1);
      float av = f0 * linv, bv = f1 * linv;
      float aq[16], bq[16];
#pragma unroll
      for (int r = 0; r < 16; r++) {
        int cr = (r & 3) + 8 * (r >> 2) + 4 * hi;
        aq[r] = __shfl(av, cr);
        bq[r] = __shfl(bv, cr);
      }
      int base = w * 4096;
#pragma unroll
      for (int db = 0; db < 4; db++)
#pragma unroll
        for (int r = 0; r < 16; r++) {
          float pv = mb[base + (db * 16 + r) * 64 + lane];
          float res = o[db][r] * aq[r] + pv * bq[r];
          int s = qg0 + (r & 3) + 8 * (r >> 2) + 4 * hi;
          int d = db * 32 + q32;
          y[(rowbase + s) * kD + h * kHd + d] = (bf)res;
        }
    }
    __syncthreads();                       // mb reads done before next staging
  }
}

}  // namespace

extern "C" void kernel_launch(void* const* d_in, const int* in_sizes, int n_in,
                              void* d_out, int out_size, void* d_ws, size_t ws_size,
                              hipStream_t stream) {
  const float* x  = (const float*)d_in[0];
  const float* Wq = (const float*)d_in[1];
  const float* Wk = (const float*)d_in[2];
  const float* Wv = (const float*)d_in[3];
  const float* Wp = (const float*)d_in[4];
  const float* qg = (const float*)d_in[5];

  // workspace layout (bf16)
  bf* xb    = (bf*)d_ws;                       // 4096*2048
  bf* wqkvb = xb + (size_t)kM * kD;            // 3072*2048 (Wq|Wk|Wv rows)
  bf* wpb   = wqkvb + (size_t)3072 * kD;       // 2048*2048
  bf* qkbuf = wpb + (size_t)kD * kD;           // 4096*2560
  bf* vtbuf = qkbuf + (size_t)kM * kQKN;       // 512*4096 (V^T: [kv d][token])
  bf* yb    = vtbuf + (size_t)512 * kM;        // 4096*2048

  cvt_kernel<<<(kM * kD / 4) / 256, 256, 0, stream>>>(x, xb, kM * kD / 4);
  cvt_kernel<<<(kD * kD / 4) / 256, 256, 0, stream>>>(Wq, wqkvb, kD * kD / 4);
  cvt_kernel<<<(512 * kD / 4) / 256, 256, 0, stream>>>(Wk, wqkvb + (size_t)kD * kD, 512 * kD / 4);
  cvt_kernel<<<(512 * kD / 4) / 256, 256, 0, stream>>>(Wv, wqkvb + (size_t)kD * kD + (size_t)512 * kD, 512 * kD / 4);
  cvt_kernel<<<(kD * kD / 4) / 256, 256, 0, stream>>>(Wp, wpb, kD * kD / 4);

  // qk = x @ [Wq;Wk]^T   (M=4096, N=2560, K=2048)
  gemm_bt<bf><<<dim3(kQKN / 128, kM / 128), 256, 0, stream>>>(xb, kD, wqkvb, kD, qkbuf, kQKN, kD);

  // V^T = Wv @ x^T       (M=512, N=4096, K=2048) -> vt[kv d][token]
  gemm_bt<bf><<<dim3(kM / 128, 512 / 128), 256, 0, stream>>>(
      wqkvb + (size_t)(kD + 512) * kD, kD, xb, kD, vtbuf, kM, kD);

  // RMSNorm + RoPE + gain (q also pre-scaled for exp2-domain softmax)
  normrope<<<(kB * kS * (kH + kKV)) / 4, 256, 0, stream>>>(qkbuf, qg);

  // flash attention -> yb
  attn_kernel<<<dim3(kB * kH, 16), 256, 0, stream>>>(qkbuf, vtbuf, yb);

  // out = yb @ Wproj^T  (M=4096, N=2048, K=2048) -> fp32 d_out
  gemm_bt<float><<<dim3(kD / 128, kM / 128), 256, 0, stream>>>(yb, kD, wpb, kD, (float*)d_out, kD, kD);
}